// Round 11
// baseline (389.598 us; speedup 1.0000x reference)
//
#include <hip/hip_runtime.h>

typedef unsigned int u32;
typedef __attribute__((ext_vector_type(8))) short short8;
typedef __attribute__((ext_vector_type(4))) float f32x4;

__device__ __forceinline__ unsigned short f2bf(float f) {
  union { float f; u32 u; } x; x.f = f;
  u32 u = x.u;
  return (unsigned short)((u + 0x7fffu + ((u >> 16) & 1u)) >> 16);
}
__device__ __forceinline__ float bf2f(unsigned short b) {
  union { u32 u; float f; } x; x.u = ((u32)b) << 16;
  return x.f;
}
__device__ __forceinline__ f32x4 mfma_bf16(short8 a, short8 b, f32x4 c) {
  return __builtin_amdgcn_mfma_f32_16x16x32_bf16(a, b, c, 0, 0, 0);
}

typedef __attribute__((address_space(3))) unsigned int lds_u32;
typedef const __attribute__((address_space(1))) unsigned int glb_u32;
__device__ __forceinline__ void gload_lds16(const unsigned short* g, unsigned short* l) {
  __builtin_amdgcn_global_load_lds((glb_u32*)g, (lds_u32*)l, 16, 0, 0);
}

// ---------------- fp32 -> bf16 conversion, x + 4 weights in ONE launch ----------------
// Launch-count reduction: 6 -> 4 kernels total. i in [0, 2M) float4:
// [0, 1M) = x, then 4 x 256K weight regions.
__global__ __launch_bounds__(256) void cvt_all(const float* __restrict__ x,
                                               const float* __restrict__ wq,
                                               const float* __restrict__ wk,
                                               const float* __restrict__ wv,
                                               const float* __restrict__ wo,
                                               unsigned short* __restrict__ xb,
                                               unsigned short* __restrict__ dqkv,
                                               unsigned short* __restrict__ dwo) {
  const int i = blockIdx.x * 256 + threadIdx.x;  // 2M float4
  const float* src;
  unsigned short* dst;
  int off;
  if (i < 1048576) {
    src = x; dst = xb; off = i;
  } else {
    const int w = (i - 1048576) >> 18;  // 0..3
    off = (i - 1048576) & 262143;
    src = (w == 0) ? wq : (w == 1) ? wk : (w == 2) ? wv : wo;
    dst = (w == 3) ? dwo : dqkv + (size_t)w * 1048576;
  }
  float4 v = ((const float4*)src)[off];
  ushort4 o;
  o.x = f2bf(v.x); o.y = f2bf(v.y); o.z = f2bf(v.z); o.w = f2bf(v.w);
  ((ushort4*)dst)[off] = o;
}

// ---------------- QKV projection GEMM + FUSED ROPE: [4096,1024] x [3072,1024]^T ------
// q,k written plain [b,s,1024] WITH RoPE applied in the epilogue; v written
// transposed [b,h,d,s] (no rope). Inner loop: R7 form (BK=64 + both-sides chunk
// swizzle) -- unchanged. RoPE fusion: output pair (d even, d+1) sits in lanes
// (l15, l15^1) at the same (i,j,r) -> one __shfl_xor(acc,1) gives the partner;
// sincos per element (aggregate ~1.7us). Kills rope_kernel's 32MB round-trip +
// one launch.
__global__ __launch_bounds__(256) void gemm_qkv(const unsigned short* __restrict__ A,
                                                const unsigned short* __restrict__ B,
                                                const int* __restrict__ pos,
                                                unsigned short* __restrict__ qk,
                                                unsigned short* __restrict__ kk,
                                                unsigned short* __restrict__ vtm) {
  constexpr int K = 1024;
  __shared__ unsigned short As[128 * 64];  // 16 KB, chunk-swizzled
  __shared__ unsigned short Bs[128 * 64];  // 16 KB
  const int tid = threadIdx.x;
  const int wave = tid >> 6, lane = tid & 63;
  const int l15 = lane & 15, quad = lane >> 4;
  const int wr = wave >> 1, wc = wave & 1;
  const int m0 = blockIdx.y * 128, n0 = blockIdx.x * 128;
  f32x4 acc[4][4] = {};
  const int srow = wave * 32 + (lane >> 3);
  const int scol = (((lane & 7) ^ ((lane >> 3) & 7)) * 8);
  const unsigned short* Ag = A + (size_t)(m0 + srow) * K + scol;
  const unsigned short* Bg = B + (size_t)(n0 + srow) * K + scol;
  const int sw0 = ((0 + quad) ^ (l15 & 7)) * 8;  // kk=0: chunk = quad
  const int sw1 = ((4 + quad) ^ (l15 & 7)) * 8;  // kk=1: chunk = 4+quad
  for (int k0 = 0; k0 < K; k0 += 64) {
    __syncthreads();
#pragma unroll
    for (int r = 0; r < 4; ++r) {
      gload_lds16(Ag + k0 + (size_t)(8 * r) * K, &As[(wave * 32 + 8 * r) * 64]);
      gload_lds16(Bg + k0 + (size_t)(8 * r) * K, &Bs[(wave * 32 + 8 * r) * 64]);
    }
    __syncthreads();
    short8 a[4][2], b[4][2];
#pragma unroll
    for (int i = 0; i < 4; ++i) {
      const int row = (wr * 64 + i * 16 + l15) * 64;
      a[i][0] = *(const short8*)&As[row + sw0];
      a[i][1] = *(const short8*)&As[row + sw1];
    }
#pragma unroll
    for (int j = 0; j < 4; ++j) {
      const int row = (wc * 64 + j * 16 + l15) * 64;
      b[j][0] = *(const short8*)&Bs[row + sw0];
      b[j][1] = *(const short8*)&Bs[row + sw1];
    }
#pragma unroll
    for (int i = 0; i < 4; ++i)
#pragma unroll
      for (int j = 0; j < 4; ++j) {
        acc[i][j] = mfma_bf16(a[i][0], b[j][0], acc[i][j]);
        acc[i][j] = mfma_bf16(a[i][1], b[j][1], acc[i][j]);
      }
  }
  const int proj = n0 >> 10;
  const int nn0 = (n0 & 1023) + wc * 64;
  if (proj < 2) {
    // ---- fused RoPE epilogue (q and k) ----
    unsigned short* dst = (proj == 0) ? qk : kk;
#pragma unroll
    for (int i = 0; i < 4; ++i) {
      const int mb = m0 + wr * 64 + i * 16 + quad * 4;
      float p4[4];
#pragma unroll
      for (int r = 0; r < 4; ++r) p4[r] = (float)pos[(mb + r) & 2047];
#pragma unroll
      for (int j = 0; j < 4; ++j) {
        const int nn = nn0 + j * 16 + l15;
        const int d = nn & 63;            // 0..63 within head
        const float inv = exp2f(-0.4152410118609203f * (float)(d >> 1));
        const bool odd = (d & 1);
#pragma unroll
        for (int r = 0; r < 4; ++r) {
          float sn, cs;
          sincosf(p4[r] * inv, &sn, &cs);
          const float a = acc[i][j][r];
          const float bp = __shfl_xor(a, 1);  // partner column (d^1), same row
          // even lane holds x1, odd lane holds x2:
          // out_even = x1*cs - x2*sn ; out_odd = x1*sn + x2*cs
          const float o = odd ? (bp * sn + a * cs) : (a * cs - bp * sn);
          dst[(size_t)(mb + r) * 1024 + nn] = f2bf(o);
        }
      }
    }
  } else {
#pragma unroll
    for (int i = 0; i < 4; ++i) {
      const int mb = m0 + wr * 64 + i * 16 + quad * 4;
      const int bb = mb >> 11, s = mb & 2047;
#pragma unroll
      for (int j = 0; j < 4; ++j) {
        const int nn = nn0 + j * 16 + l15;
        const int h = nn >> 6, d = nn & 63;
        ushort4 v4;
        v4.x = f2bf(acc[i][j][0]); v4.y = f2bf(acc[i][j][1]);
        v4.z = f2bf(acc[i][j][2]); v4.w = f2bf(acc[i][j][3]);
        *(ushort4*)&vtm[(((size_t)bb * 16 + h) * 64 + d) * 2048 + s] = v4;
      }
    }
  }
}

// ---------------- flash attention (causal), 4 waves / block, COUNTED-VMCNT pipeline --
// R10 form (best measured: 69.4 us). Unchanged this round (attribution anchor).
__global__ __launch_bounds__(256) void attn_shared(const unsigned short* __restrict__ qk,
                                                   const unsigned short* __restrict__ kk,
                                                   const unsigned short* __restrict__ vtm,
                                                   unsigned short* __restrict__ om) {
  __shared__ unsigned short Ks[2][64 * 64];  // 16 KB, swizzled cols, double-buffered
  __shared__ unsigned short Vs[2][64 * 64];  // 16 KB
  __shared__ u32 PTb[4][2][16 * 36];         // 18 KB, per-wave per-f P^T
  const int tid = threadIdx.x;
  const int wave = tid >> 6, lane = tid & 63;
  const int l15 = lane & 15, quad = lane >> 4;
  u32* PT0 = &PTb[wave][0][0];
  u32* PT1 = &PTb[wave][1][0];
  const int bid = blockIdx.x;
  const int bh = bid & 31;           // bh%8 == bid%8 -> per-XCD K/V locality
  const int qblk = 15 - (bid >> 5);  // longest blocks dispatched first
  const int b = bh >> 4, h = bh & 15;
  const int qbase = qblk * 128 + wave * 32;  // this wave's 32-row Q tile
  const unsigned short* Qp = qk + (size_t)b * 2048 * 1024 + h * 64;
  const unsigned short* Kp = kk + (size_t)b * 2048 * 1024 + h * 64;
  const unsigned short* Vp = vtm + (size_t)bh * 64 * 2048;  // [d][s]
  short8 qf[2][2];
#pragma unroll
  for (int f = 0; f < 2; ++f)
#pragma unroll
    for (int hh = 0; hh < 2; ++hh)
      qf[f][hh] = *(const short8*)(Qp + (size_t)(qbase + f * 16 + l15) * 1024 + hh * 32 + quad * 8);
  f32x4 o4[2][4] = {};
  f32x4 ls[2] = {};
  short8 ones;
#pragma unroll
  for (int j = 0; j < 8; ++j) ones[j] = (short)0x3F80;  // bf16 1.0
  const float SC = 0.18033688011112042f;  // 0.125 * log2(e)
  const int nkb = (qblk * 128 + 191) >> 6;  // block tile count
  const int nkw = (qbase + 95) >> 6;        // this wave's tile count
  const int srow = wave * 16 + (lane >> 3);
  const int scs = (((lane & 7) ^ (srow & 7)) * 8);
  const unsigned short* KgB = Kp + (size_t)srow * 1024 + scs;
  const unsigned short* VgB = Vp + (size_t)srow * 2048 + scs;
  const int l0 = (wave * 16) * 64;
  const int l1 = (wave * 16 + 8) * 64;
  const int sw0 = ((quad ^ (l15 & 7)) * 8);        // hh=0: c16 = quad
  const int sw1 = (((4 + quad) ^ (l15 & 7)) * 8);  // hh=1: c16 = 4+quad
#define ATTN_STAGE(c, kb)                                              \
  do {                                                                 \
    gload_lds16(KgB + (size_t)(kb) * 1024, &Ks[c][l0]);                \
    gload_lds16(KgB + (size_t)(kb) * 1024 + 8 * 1024, &Ks[c][l1]);     \
    gload_lds16(VgB + (kb), &Vs[c][l0]);                               \
    gload_lds16(VgB + (kb) + 8 * 2048, &Vs[c][l1]);                    \
  } while (0)
  ATTN_STAGE(0, 0);
  int cur = 0;
  for (int kt = 0; kt < nkb; ++kt) {
    __builtin_amdgcn_s_barrier();  // all waves done reading buf[cur^1] (prev iter)
    const int knext = (kt + 1 < nkb ? kt + 1 : kt) << 6;  // clamp: redundant reload
    ATTN_STAGE(cur ^ 1, knext);
    // tile-kt loads (issued a full iteration ago) landed; 4 just-issued stay in flight
    asm volatile("s_waitcnt vmcnt(4)" ::: "memory");
    __builtin_amdgcn_s_barrier();  // everyone's tile-kt data visible
    __builtin_amdgcn_sched_barrier(0);
    if (kt < nkw) {
      const int kbase = kt << 6;
      short8 kb[4][2], vb[4][2];
#pragma unroll
      for (int nt = 0; nt < 4; ++nt) {
        kb[nt][0] = *(const short8*)&Ks[cur][(nt * 16 + l15) * 64 + sw0];
        kb[nt][1] = *(const short8*)&Ks[cur][(nt * 16 + l15) * 64 + sw1];
      }
#pragma unroll
      for (int t = 0; t < 4; ++t) {
        vb[t][0] = *(const short8*)&Vs[cur][(t * 16 + l15) * 64 + sw0];
        vb[t][1] = *(const short8*)&Vs[cur][(t * 16 + l15) * 64 + sw1];
      }
      // swapped QK^T: A=K, B=Q -> lane holds S[q=l15][kv=nt*16+quad*4+r]
      f32x4 s4[2][4] = {};
#pragma unroll
      for (int f = 0; f < 2; ++f)
#pragma unroll
        for (int nt = 0; nt < 4; ++nt) {
          s4[f][nt] = mfma_bf16(kb[nt][0], qf[f][0], s4[f][nt]);
          s4[f][nt] = mfma_bf16(kb[nt][1], qf[f][1], s4[f][nt]);
        }
      const bool edge = (kbase + 63 > qbase);
#pragma unroll
      for (int f = 0; f < 2; ++f) {
        const int qrow = qbase + f * 16 + l15;
        u32* PTf = f ? PT1 : PT0;
#pragma unroll
        for (int nt = 0; nt < 4; ++nt) {
          const int kv0 = kbase + nt * 16 + quad * 4;
          float p0 = exp2f(s4[f][nt][0] * SC);
          float p1 = exp2f(s4[f][nt][1] * SC);
          float p2 = exp2f(s4[f][nt][2] * SC);
          float p3 = exp2f(s4[f][nt][3] * SC);
          if (edge) {
            if (kv0 > qrow) p0 = 0.f;
            if (kv0 + 1 > qrow) p1 = 0.f;
            if (kv0 + 2 > qrow) p2 = 0.f;
            if (kv0 + 3 > qrow) p3 = 0.f;
          }
          uint2 w;
          w.x = (u32)f2bf(p0) | ((u32)f2bf(p1) << 16);
          w.y = (u32)f2bf(p2) | ((u32)f2bf(p3) << 16);
          *(uint2*)&PTf[l15 * 36 + nt * 8 + quad * 2] = w;  // b64, 8B aligned
        }
      }
      // compiler inserts precise lgkmcnt for the write->read dependency (same object)
      short8 pa[2][2];
#pragma unroll
      for (int f = 0; f < 2; ++f) {
        const u32* PTf = f ? PT1 : PT0;
#pragma unroll
        for (int hh = 0; hh < 2; ++hh)
          pa[f][hh] = *(const short8*)&PTf[l15 * 36 + hh * 16 + quad * 4];  // b128, 16B aligned
      }
#pragma unroll
      for (int f = 0; f < 2; ++f) {
#pragma unroll
        for (int t = 0; t < 4; ++t) {
          o4[f][t] = mfma_bf16(pa[f][0], vb[t][0], o4[f][t]);
          o4[f][t] = mfma_bf16(pa[f][1], vb[t][1], o4[f][t]);
        }
        ls[f] = mfma_bf16(pa[f][0], ones, ls[f]);
        ls[f] = mfma_bf16(pa[f][1], ones, ls[f]);
      }
    }
    cur ^= 1;
  }
#undef ATTN_STAGE
#pragma unroll
  for (int f = 0; f < 2; ++f) {
    f32x4 rl;
#pragma unroll
    for (int r = 0; r < 4; ++r) rl[r] = 1.f / ls[f][r];
#pragma unroll
    for (int t = 0; t < 4; ++t)
#pragma unroll
      for (int r = 0; r < 4; ++r) {
        const int srw = qbase + f * 16 + quad * 4 + r;
        om[((size_t)b * 2048 + srw) * 1024 + h * 64 + t * 16 + l15] = f2bf(o4[f][t][r] * rl[r]);
      }
  }
}

// ---------------- output projection GEMM: [4096,1024] x [1024,1024]^T -> fp32 ----------------
// R7 form (BK=64 + chunk swizzle). Unchanged this round.
__global__ __launch_bounds__(256) void gemm_out(const unsigned short* __restrict__ A,
                                                const unsigned short* __restrict__ B,
                                                float* __restrict__ C) {
  constexpr int K = 1024;
  __shared__ unsigned short As[64 * 64];   // 8 KB
  __shared__ unsigned short Bs[128 * 64];  // 16 KB
  const int tid = threadIdx.x;
  const int wave = tid >> 6, lane = tid & 63;
  const int l15 = lane & 15, quad = lane >> 4;
  const int m0 = blockIdx.y * 64, n0 = blockIdx.x * 128;
  f32x4 acc[4][2] = {};
  const int lr = lane >> 3;
  const int scol = (((lane & 7) ^ (lr & 7)) * 8);
  const unsigned short* Ag = A + (size_t)(m0 + wave * 16 + lr) * K + scol;
  const unsigned short* Bg = B + (size_t)(n0 + wave * 32 + lr) * K + scol;
  const int sw0 = ((0 + quad) ^ (l15 & 7)) * 8;
  const int sw1 = ((4 + quad) ^ (l15 & 7)) * 8;
  for (int k0 = 0; k0 < K; k0 += 64) {
    __syncthreads();
    gload_lds16(Ag + k0, &As[(wave * 16) * 64]);
    gload_lds16(Ag + k0 + (size_t)8 * K, &As[(wave * 16 + 8) * 64]);
#pragma unroll
    for (int r = 0; r < 4; ++r)
      gload_lds16(Bg + k0 + (size_t)(8 * r) * K, &Bs[(wave * 32 + 8 * r) * 64]);
    __syncthreads();
    short8 a[4][2], b[2][2];
#pragma unroll
    for (int i = 0; i < 4; ++i) {
      const int row = (i * 16 + l15) * 64;
      a[i][0] = *(const short8*)&As[row + sw0];
      a[i][1] = *(const short8*)&As[row + sw1];
    }
#pragma unroll
    for (int j = 0; j < 2; ++j) {
      const int row = (wave * 32 + j * 16 + l15) * 64;
      b[j][0] = *(const short8*)&Bs[row + sw0];
      b[j][1] = *(const short8*)&Bs[row + sw1];
    }
#pragma unroll
    for (int i = 0; i < 4; ++i)
#pragma unroll
      for (int j = 0; j < 2; ++j) {
        acc[i][j] = mfma_bf16(a[i][0], b[j][0], acc[i][j]);
        acc[i][j] = mfma_bf16(a[i][1], b[j][1], acc[i][j]);
      }
  }
#pragma unroll
  for (int i = 0; i < 4; ++i)
#pragma unroll
    for (int j = 0; j < 2; ++j)
#pragma unroll
      for (int r = 0; r < 4; ++r)
        C[(size_t)(m0 + i * 16 + quad * 4 + r) * 1024 + n0 + wave * 32 + j * 16 + l15] =
            acc[i][j][r];
}

extern "C" void kernel_launch(void* const* d_in, const int* in_sizes, int n_in,
                              void* d_out, int out_size, void* d_ws, size_t ws_size,
                              hipStream_t stream) {
  const float* x  = (const float*)d_in[0];
  const int* pos  = (const int*)d_in[1];
  const float* Wq = (const float*)d_in[2];
  const float* Wk = (const float*)d_in[3];
  const float* Wv = (const float*)d_in[4];
  const float* Wo = (const float*)d_in[5];
  float* out = (float*)d_out;
  char* ws = (char*)d_ws;
  unsigned short* xb   = (unsigned short*)(ws);                      // 8 MB  [4096,1024]
  unsigned short* wqkv = (unsigned short*)(ws + (size_t)( 8 << 20)); // 6 MB  [3072,1024]
  unsigned short* wob  = (unsigned short*)(ws + (size_t)(14 << 20)); // 2 MB  [1024,1024]
  unsigned short* qkb  = (unsigned short*)(ws + (size_t)(16 << 20)); // 8 MB  [2,2048,1024]
  unsigned short* kkb  = (unsigned short*)(ws + (size_t)(24 << 20)); // 8 MB
  unsigned short* vtm  = (unsigned short*)(ws + (size_t)(32 << 20)); // 8 MB  [2,16,64,2048]
  unsigned short* om   = (unsigned short*)(ws + (size_t)(40 << 20)); // 8 MB  [4096,1024]

  // 2M float4 total: 1M (x) + 4 x 256K (weights)
  hipLaunchKernelGGL(cvt_all, dim3(8192), dim3(256), 0, stream, x, Wq, Wk, Wv, Wo,
                     xb, wqkv, wob);
  hipLaunchKernelGGL(gemm_qkv, dim3(24, 32), dim3(256), 0, stream, xb, wqkv, pos,
                     qkb, kkb, vtm);
  hipLaunchKernelGGL(attn_shared, dim3(512), dim3(256), 0, stream, qkb, kkb, vtm, om);
  hipLaunchKernelGGL(gemm_out, dim3(8, 64), dim3(256), 0, stream, om, wob, out);
}

// Round 13
// 205.644 us; speedup vs baseline: 1.8945x; 1.8945x over previous
//
#include <hip/hip_runtime.h>

typedef unsigned int u32;
typedef __attribute__((ext_vector_type(8))) short short8;
typedef __attribute__((ext_vector_type(4))) float f32x4;

__device__ __forceinline__ unsigned short f2bf(float f) {
  union { float f; u32 u; } x; x.f = f;
  u32 u = x.u;
  return (unsigned short)((u + 0x7fffu + ((u >> 16) & 1u)) >> 16);
}
__device__ __forceinline__ float bf2f(unsigned short b) {
  union { u32 u; float f; } x; x.u = ((u32)b) << 16;
  return x.f;
}
__device__ __forceinline__ f32x4 mfma_bf16(short8 a, short8 b, f32x4 c) {
  return __builtin_amdgcn_mfma_f32_16x16x32_bf16(a, b, c, 0, 0, 0);
}

typedef __attribute__((address_space(3))) unsigned int lds_u32;
typedef const __attribute__((address_space(1))) unsigned int glb_u32;
__device__ __forceinline__ void gload_lds16(const unsigned short* g, unsigned short* l) {
  __builtin_amdgcn_global_load_lds((glb_u32*)g, (lds_u32*)l, 16, 0, 0);
}

// ---------------- fp32 -> bf16 conversion, x + 4 weights in ONE launch ----------------
__global__ __launch_bounds__(256) void cvt_all(const float* __restrict__ x,
                                               const float* __restrict__ wq,
                                               const float* __restrict__ wk,
                                               const float* __restrict__ wv,
                                               const float* __restrict__ wo,
                                               unsigned short* __restrict__ xb,
                                               unsigned short* __restrict__ dqkv,
                                               unsigned short* __restrict__ dwo) {
  const int i = blockIdx.x * 256 + threadIdx.x;  // 2M float4
  const float* src;
  unsigned short* dst;
  int off;
  if (i < 1048576) {
    src = x; dst = xb; off = i;
  } else {
    const int w = (i - 1048576) >> 18;  // 0..3
    off = (i - 1048576) & 262143;
    src = (w == 0) ? wq : (w == 1) ? wk : (w == 2) ? wv : wo;
    dst = (w == 3) ? dwo : dqkv + (size_t)w * 1048576;
  }
  float4 v = ((const float4*)src)[off];
  ushort4 o;
  o.x = f2bf(v.x); o.y = f2bf(v.y); o.z = f2bf(v.z); o.w = f2bf(v.w);
  ((ushort4*)dst)[off] = o;
}

// ---------------- QKV projection GEMM + FUSED ROPE: [4096,1024] x [3072,1024]^T ------
// R11 POST-MORTEM: sincosf is a REAL OCML CALL -> call ABI spilled the 64 live acc
// VGPRs to scratch (WRITE_SIZE 803 MB, VGPR 60, 244us). Fusion math was correct.
// Fix: call-free HW trig -- v_sin_f32/v_cos_f32 take REVOLUTIONS (ISA doc), so fold
// 1/2pi into the freq constant, fract via floorf (v_floor inline), then
// __builtin_amdgcn_sinf/cosf (single VALU ops, no ABI clobber, no spills).
// Precision: angle <= ~326 rev -> fp32 ulp ~3e-5 rev ~ 1.9e-4 rad, << bf16 quantum.
// Inner loop: R7 form (BK=64 + both-sides chunk swizzle), unchanged.
__global__ __launch_bounds__(256) void gemm_qkv(const unsigned short* __restrict__ A,
                                                const unsigned short* __restrict__ B,
                                                const int* __restrict__ pos,
                                                unsigned short* __restrict__ qk,
                                                unsigned short* __restrict__ kk,
                                                unsigned short* __restrict__ vtm) {
  constexpr int K = 1024;
  __shared__ unsigned short As[128 * 64];  // 16 KB, chunk-swizzled
  __shared__ unsigned short Bs[128 * 64];  // 16 KB
  const int tid = threadIdx.x;
  const int wave = tid >> 6, lane = tid & 63;
  const int l15 = lane & 15, quad = lane >> 4;
  const int wr = wave >> 1, wc = wave & 1;
  const int m0 = blockIdx.y * 128, n0 = blockIdx.x * 128;
  f32x4 acc[4][4] = {};
  const int srow = wave * 32 + (lane >> 3);
  const int scol = (((lane & 7) ^ ((lane >> 3) & 7)) * 8);
  const unsigned short* Ag = A + (size_t)(m0 + srow) * K + scol;
  const unsigned short* Bg = B + (size_t)(n0 + srow) * K + scol;
  const int sw0 = ((0 + quad) ^ (l15 & 7)) * 8;  // kk=0: chunk = quad
  const int sw1 = ((4 + quad) ^ (l15 & 7)) * 8;  // kk=1: chunk = 4+quad
  for (int k0 = 0; k0 < K; k0 += 64) {
    __syncthreads();
#pragma unroll
    for (int r = 0; r < 4; ++r) {
      gload_lds16(Ag + k0 + (size_t)(8 * r) * K, &As[(wave * 32 + 8 * r) * 64]);
      gload_lds16(Bg + k0 + (size_t)(8 * r) * K, &Bs[(wave * 32 + 8 * r) * 64]);
    }
    __syncthreads();
    short8 a[4][2], b[4][2];
#pragma unroll
    for (int i = 0; i < 4; ++i) {
      const int row = (wr * 64 + i * 16 + l15) * 64;
      a[i][0] = *(const short8*)&As[row + sw0];
      a[i][1] = *(const short8*)&As[row + sw1];
    }
#pragma unroll
    for (int j = 0; j < 4; ++j) {
      const int row = (wc * 64 + j * 16 + l15) * 64;
      b[j][0] = *(const short8*)&Bs[row + sw0];
      b[j][1] = *(const short8*)&Bs[row + sw1];
    }
#pragma unroll
    for (int i = 0; i < 4; ++i)
#pragma unroll
      for (int j = 0; j < 4; ++j) {
        acc[i][j] = mfma_bf16(a[i][0], b[j][0], acc[i][j]);
        acc[i][j] = mfma_bf16(a[i][1], b[j][1], acc[i][j]);
      }
  }
  const int proj = n0 >> 10;
  const int nn0 = (n0 & 1023) + wc * 64;
  if (proj < 2) {
    // ---- fused RoPE epilogue (q and k), call-free trig ----
    unsigned short* dst = (proj == 0) ? qk : kk;
    const float INV2PI = 0.15915494309189535f;
#pragma unroll
    for (int i = 0; i < 4; ++i) {
      const int mb = m0 + wr * 64 + i * 16 + quad * 4;
      float p4[4];
#pragma unroll
      for (int r = 0; r < 4; ++r) p4[r] = (float)pos[(mb + r) & 2047];
#pragma unroll
      for (int j = 0; j < 4; ++j) {
        const int nn = nn0 + j * 16 + l15;
        const int d = nn & 63;            // 0..63 within head
        const float inv_rev = exp2f(-0.4152410118609203f * (float)(d >> 1)) * INV2PI;
        const bool odd = (d & 1);
#pragma unroll
        for (int r = 0; r < 4; ++r) {
          float ang = p4[r] * inv_rev;    // revolutions
          ang -= floorf(ang);             // v_fract equivalent, [0,1)
          const float sn = __builtin_amdgcn_sinf(ang);  // v_sin_f32: sin(2*pi*ang)
          const float cs = __builtin_amdgcn_cosf(ang);  // v_cos_f32
          const float a = acc[i][j][r];
          const float bp = __shfl_xor(a, 1);  // partner column (d^1), same row
          const float o = odd ? (bp * sn + a * cs) : (a * cs - bp * sn);
          dst[(size_t)(mb + r) * 1024 + nn] = f2bf(o);
        }
      }
    }
  } else {
#pragma unroll
    for (int i = 0; i < 4; ++i) {
      const int mb = m0 + wr * 64 + i * 16 + quad * 4;
      const int bb = mb >> 11, s = mb & 2047;
#pragma unroll
      for (int j = 0; j < 4; ++j) {
        const int nn = nn0 + j * 16 + l15;
        const int h = nn >> 6, d = nn & 63;
        ushort4 v4;
        v4.x = f2bf(acc[i][j][0]); v4.y = f2bf(acc[i][j][1]);
        v4.z = f2bf(acc[i][j][2]); v4.w = f2bf(acc[i][j][3]);
        *(ushort4*)&vtm[(((size_t)bb * 16 + h) * 64 + d) * 2048 + s] = v4;
      }
    }
  }
}

// ---------------- flash attention (causal), 4 waves / block, COUNTED-VMCNT pipeline --
// R10 form (best measured: 69.4 us). Unchanged.
__global__ __launch_bounds__(256) void attn_shared(const unsigned short* __restrict__ qk,
                                                   const unsigned short* __restrict__ kk,
                                                   const unsigned short* __restrict__ vtm,
                                                   unsigned short* __restrict__ om) {
  __shared__ unsigned short Ks[2][64 * 64];  // 16 KB, swizzled cols, double-buffered
  __shared__ unsigned short Vs[2][64 * 64];  // 16 KB
  __shared__ u32 PTb[4][2][16 * 36];         // 18 KB, per-wave per-f P^T
  const int tid = threadIdx.x;
  const int wave = tid >> 6, lane = tid & 63;
  const int l15 = lane & 15, quad = lane >> 4;
  u32* PT0 = &PTb[wave][0][0];
  u32* PT1 = &PTb[wave][1][0];
  const int bid = blockIdx.x;
  const int bh = bid & 31;           // bh%8 == bid%8 -> per-XCD K/V locality
  const int qblk = 15 - (bid >> 5);  // longest blocks dispatched first
  const int b = bh >> 4, h = bh & 15;
  const int qbase = qblk * 128 + wave * 32;  // this wave's 32-row Q tile
  const unsigned short* Qp = qk + (size_t)b * 2048 * 1024 + h * 64;
  const unsigned short* Kp = kk + (size_t)b * 2048 * 1024 + h * 64;
  const unsigned short* Vp = vtm + (size_t)bh * 64 * 2048;  // [d][s]
  short8 qf[2][2];
#pragma unroll
  for (int f = 0; f < 2; ++f)
#pragma unroll
    for (int hh = 0; hh < 2; ++hh)
      qf[f][hh] = *(const short8*)(Qp + (size_t)(qbase + f * 16 + l15) * 1024 + hh * 32 + quad * 8);
  f32x4 o4[2][4] = {};
  f32x4 ls[2] = {};
  short8 ones;
#pragma unroll
  for (int j = 0; j < 8; ++j) ones[j] = (short)0x3F80;  // bf16 1.0
  const float SC = 0.18033688011112042f;  // 0.125 * log2(e)
  const int nkb = (qblk * 128 + 191) >> 6;  // block tile count
  const int nkw = (qbase + 95) >> 6;        // this wave's tile count
  const int srow = wave * 16 + (lane >> 3);
  const int scs = (((lane & 7) ^ (srow & 7)) * 8);
  const unsigned short* KgB = Kp + (size_t)srow * 1024 + scs;
  const unsigned short* VgB = Vp + (size_t)srow * 2048 + scs;
  const int l0 = (wave * 16) * 64;
  const int l1 = (wave * 16 + 8) * 64;
  const int sw0 = ((quad ^ (l15 & 7)) * 8);        // hh=0: c16 = quad
  const int sw1 = (((4 + quad) ^ (l15 & 7)) * 8);  // hh=1: c16 = 4+quad
#define ATTN_STAGE(c, kb)                                              \
  do {                                                                 \
    gload_lds16(KgB + (size_t)(kb) * 1024, &Ks[c][l0]);                \
    gload_lds16(KgB + (size_t)(kb) * 1024 + 8 * 1024, &Ks[c][l1]);     \
    gload_lds16(VgB + (kb), &Vs[c][l0]);                               \
    gload_lds16(VgB + (kb) + 8 * 2048, &Vs[c][l1]);                    \
  } while (0)
  ATTN_STAGE(0, 0);
  int cur = 0;
  for (int kt = 0; kt < nkb; ++kt) {
    __builtin_amdgcn_s_barrier();  // all waves done reading buf[cur^1] (prev iter)
    const int knext = (kt + 1 < nkb ? kt + 1 : kt) << 6;  // clamp: redundant reload
    ATTN_STAGE(cur ^ 1, knext);
    // tile-kt loads (issued a full iteration ago) landed; 4 just-issued stay in flight
    asm volatile("s_waitcnt vmcnt(4)" ::: "memory");
    __builtin_amdgcn_s_barrier();  // everyone's tile-kt data visible
    __builtin_amdgcn_sched_barrier(0);
    if (kt < nkw) {
      const int kbase = kt << 6;
      short8 kb[4][2], vb[4][2];
#pragma unroll
      for (int nt = 0; nt < 4; ++nt) {
        kb[nt][0] = *(const short8*)&Ks[cur][(nt * 16 + l15) * 64 + sw0];
        kb[nt][1] = *(const short8*)&Ks[cur][(nt * 16 + l15) * 64 + sw1];
      }
#pragma unroll
      for (int t = 0; t < 4; ++t) {
        vb[t][0] = *(const short8*)&Vs[cur][(t * 16 + l15) * 64 + sw0];
        vb[t][1] = *(const short8*)&Vs[cur][(t * 16 + l15) * 64 + sw1];
      }
      // swapped QK^T: A=K, B=Q -> lane holds S[q=l15][kv=nt*16+quad*4+r]
      f32x4 s4[2][4] = {};
#pragma unroll
      for (int f = 0; f < 2; ++f)
#pragma unroll
        for (int nt = 0; nt < 4; ++nt) {
          s4[f][nt] = mfma_bf16(kb[nt][0], qf[f][0], s4[f][nt]);
          s4[f][nt] = mfma_bf16(kb[nt][1], qf[f][1], s4[f][nt]);
        }
      const bool edge = (kbase + 63 > qbase);
#pragma unroll
      for (int f = 0; f < 2; ++f) {
        const int qrow = qbase + f * 16 + l15;
        u32* PTf = f ? PT1 : PT0;
#pragma unroll
        for (int nt = 0; nt < 4; ++nt) {
          const int kv0 = kbase + nt * 16 + quad * 4;
          float p0 = exp2f(s4[f][nt][0] * SC);
          float p1 = exp2f(s4[f][nt][1] * SC);
          float p2 = exp2f(s4[f][nt][2] * SC);
          float p3 = exp2f(s4[f][nt][3] * SC);
          if (edge) {
            if (kv0 > qrow) p0 = 0.f;
            if (kv0 + 1 > qrow) p1 = 0.f;
            if (kv0 + 2 > qrow) p2 = 0.f;
            if (kv0 + 3 > qrow) p3 = 0.f;
          }
          uint2 w;
          w.x = (u32)f2bf(p0) | ((u32)f2bf(p1) << 16);
          w.y = (u32)f2bf(p2) | ((u32)f2bf(p3) << 16);
          *(uint2*)&PTf[l15 * 36 + nt * 8 + quad * 2] = w;  // b64, 8B aligned
        }
      }
      // compiler inserts precise lgkmcnt for the write->read dependency (same object)
      short8 pa[2][2];
#pragma unroll
      for (int f = 0; f < 2; ++f) {
        const u32* PTf = f ? PT1 : PT0;
#pragma unroll
        for (int hh = 0; hh < 2; ++hh)
          pa[f][hh] = *(const short8*)&PTf[l15 * 36 + hh * 16 + quad * 4];  // b128, 16B aligned
      }
#pragma unroll
      for (int f = 0; f < 2; ++f) {
#pragma unroll
        for (int t = 0; t < 4; ++t) {
          o4[f][t] = mfma_bf16(pa[f][0], vb[t][0], o4[f][t]);
          o4[f][t] = mfma_bf16(pa[f][1], vb[t][1], o4[f][t]);
        }
        ls[f] = mfma_bf16(pa[f][0], ones, ls[f]);
        ls[f] = mfma_bf16(pa[f][1], ones, ls[f]);
      }
    }
    cur ^= 1;
  }
#undef ATTN_STAGE
#pragma unroll
  for (int f = 0; f < 2; ++f) {
    f32x4 rl;
#pragma unroll
    for (int r = 0; r < 4; ++r) rl[r] = 1.f / ls[f][r];
#pragma unroll
    for (int t = 0; t < 4; ++t)
#pragma unroll
      for (int r = 0; r < 4; ++r) {
        const int srw = qbase + f * 16 + quad * 4 + r;
        om[((size_t)b * 2048 + srw) * 1024 + h * 64 + t * 16 + l15] = f2bf(o4[f][t][r] * rl[r]);
      }
  }
}

// ---------------- output projection GEMM: [4096,1024] x [1024,1024]^T -> fp32 ----------------
// R7 form (BK=64 + chunk swizzle). Unchanged.
__global__ __launch_bounds__(256) void gemm_out(const unsigned short* __restrict__ A,
                                                const unsigned short* __restrict__ B,
                                                float* __restrict__ C) {
  constexpr int K = 1024;
  __shared__ unsigned short As[64 * 64];   // 8 KB
  __shared__ unsigned short Bs[128 * 64];  // 16 KB
  const int tid = threadIdx.x;
  const int wave = tid >> 6, lane = tid & 63;
  const int l15 = lane & 15, quad = lane >> 4;
  const int m0 = blockIdx.y * 64, n0 = blockIdx.x * 128;
  f32x4 acc[4][2] = {};
  const int lr = lane >> 3;
  const int scol = (((lane & 7) ^ (lr & 7)) * 8);
  const unsigned short* Ag = A + (size_t)(m0 + wave * 16 + lr) * K + scol;
  const unsigned short* Bg = B + (size_t)(n0 + wave * 32 + lr) * K + scol;
  const int sw0 = ((0 + quad) ^ (l15 & 7)) * 8;
  const int sw1 = ((4 + quad) ^ (l15 & 7)) * 8;
  for (int k0 = 0; k0 < K; k0 += 64) {
    __syncthreads();
    gload_lds16(Ag + k0, &As[(wave * 16) * 64]);
    gload_lds16(Ag + k0 + (size_t)8 * K, &As[(wave * 16 + 8) * 64]);
#pragma unroll
    for (int r = 0; r < 4; ++r)
      gload_lds16(Bg + k0 + (size_t)(8 * r) * K, &Bs[(wave * 32 + 8 * r) * 64]);
    __syncthreads();
    short8 a[4][2], b[2][2];
#pragma unroll
    for (int i = 0; i < 4; ++i) {
      const int row = (i * 16 + l15) * 64;
      a[i][0] = *(const short8*)&As[row + sw0];
      a[i][1] = *(const short8*)&As[row + sw1];
    }
#pragma unroll
    for (int j = 0; j < 2; ++j) {
      const int row = (wave * 32 + j * 16 + l15) * 64;
      b[j][0] = *(const short8*)&Bs[row + sw0];
      b[j][1] = *(const short8*)&Bs[row + sw1];
    }
#pragma unroll
    for (int i = 0; i < 4; ++i)
#pragma unroll
      for (int j = 0; j < 2; ++j) {
        acc[i][j] = mfma_bf16(a[i][0], b[j][0], acc[i][j]);
        acc[i][j] = mfma_bf16(a[i][1], b[j][1], acc[i][j]);
      }
  }
#pragma unroll
  for (int i = 0; i < 4; ++i)
#pragma unroll
    for (int j = 0; j < 2; ++j)
#pragma unroll
      for (int r = 0; r < 4; ++r)
        C[(size_t)(m0 + i * 16 + quad * 4 + r) * 1024 + n0 + wave * 32 + j * 16 + l15] =
            acc[i][j][r];
}

extern "C" void kernel_launch(void* const* d_in, const int* in_sizes, int n_in,
                              void* d_out, int out_size, void* d_ws, size_t ws_size,
                              hipStream_t stream) {
  const float* x  = (const float*)d_in[0];
  const int* pos  = (const int*)d_in[1];
  const float* Wq = (const float*)d_in[2];
  const float* Wk = (const float*)d_in[3];
  const float* Wv = (const float*)d_in[4];
  const float* Wo = (const float*)d_in[5];
  float* out = (float*)d_out;
  char* ws = (char*)d_ws;
  unsigned short* xb   = (unsigned short*)(ws);                      // 8 MB  [4096,1024]
  unsigned short* wqkv = (unsigned short*)(ws + (size_t)( 8 << 20)); // 6 MB  [3072,1024]
  unsigned short* wob  = (unsigned short*)(ws + (size_t)(14 << 20)); // 2 MB  [1024,1024]
  unsigned short* qkb  = (unsigned short*)(ws + (size_t)(16 << 20)); // 8 MB  [2,2048,1024]
  unsigned short* kkb  = (unsigned short*)(ws + (size_t)(24 << 20)); // 8 MB
  unsigned short* vtm  = (unsigned short*)(ws + (size_t)(32 << 20)); // 8 MB  [2,16,64,2048]
  unsigned short* om   = (unsigned short*)(ws + (size_t)(40 << 20)); // 8 MB  [4096,1024]

  // 2M float4 total: 1M (x) + 4 x 256K (weights)
  hipLaunchKernelGGL(cvt_all, dim3(8192), dim3(256), 0, stream, x, Wq, Wk, Wv, Wo,
                     xb, wqkv, wob);
  hipLaunchKernelGGL(gemm_qkv, dim3(24, 32), dim3(256), 0, stream, xb, wqkv, pos,
                     qkb, kkb, vtm);
  hipLaunchKernelGGL(attn_shared, dim3(512), dim3(256), 0, stream, qkb, kkb, vtm, om);
  hipLaunchKernelGGL(gemm_out, dim3(8, 64), dim3(256), 0, stream, om, wob, out);
}